// Round 5
// baseline (227.099 us; speedup 1.0000x reference)
//
#include <hip/hip_runtime.h>
#include <hip/hip_bf16.h>

#define HW   4096

typedef __bf16 bf_t;
typedef __bf16 bf8_t __attribute__((ext_vector_type(8)));
typedef __bf16 bf2_t __attribute__((ext_vector_type(2)));
typedef float  f4_t  __attribute__((ext_vector_type(4)));
typedef float  f2_t  __attribute__((ext_vector_type(2)));
typedef int    i4_t  __attribute__((ext_vector_type(4)));

// Static device workspace (element offsets into g_ws, in floats):
#define OFF_A    0              // 2*50*HW NCHW offset maps
#define OFF_B    409600         // 2*98*HW
#define A1_F32   1212416        // NHWC fp32 [b][4096][64] = 524288 each
#define B1_F32   1736704
#define A2_F32   2260992
#define B2_F32   2785280
#define XA_F32   3309568
#define XB_F32   3833856
#define XA_HI    4358144        // bf16 NHWC = 262144 floats each
#define XA_LO    4620288
#define XB_HI    4882432
#define XB_LO    5144576
#define A1_HI    5406720
#define A1_LO    5668864
#define B1_HI    5931008
#define B1_LO    6193152
#define AW_A1    6455296        // conv weight packs (bf16 A-frag)
#define AW_B1    6464512
#define AW_A2    6515712
#define AW_B2    6566912
#define DW_A1    6767616        // depthwise weights transposed [KK][64]
#define DW_B1    6768192
#define DW_A2    6769792
#define DW_B2    6771392
#define WS_TOT   6774528

__device__ __align__(16) float g_ws[WS_TOT];

__device__ __forceinline__ bf8_t bf8_zero() {
    bf8_t v;
#pragma unroll
    for (int j = 0; j < 8; ++j) v[j] = (bf_t)0.f;
    return v;
}

// ---------------------------------------------------------------------------
// Weight prep helpers (range-dispatched).
// ---------------------------------------------------------------------------
__device__ __forceinline__ void prep_wA_dev(const float* wg, int aw_off,
                                            int Cout, int K, int NCOT, int lb) {
    const int KK = K * K;
    const int total = KK * NCOT * 128;
    const int idx = lb * 256 + threadIdx.x;
    if (idx >= total) return;
    bf_t* aw = (bf_t*)(g_ws + aw_off);
    int lane = idx & 63;
    int kh   = (idx >> 6) & 1;
    int cot  = (idx >> 7) % NCOT;
    int tap  = idx / (128 * NCOT);
    int co   = cot * 16 + (lane & 15);
    int ci0  = kh * 32 + (lane >> 4) * 8;
    bf8_t v;
#pragma unroll
    for (int j = 0; j < 8; ++j) {
        float f = (co < Cout) ? wg[(co * 64 + ci0 + j) * KK + tap] : 0.f;
        v[j] = (bf_t)f;
    }
    *(bf8_t*)&aw[(long)idx * 8] = v;
}

__device__ __forceinline__ void prep_dwT_dev(const float* w, int dst_off,
                                             int KK, int lb) {
    const int idx = lb * 256 + threadIdx.x;
    if (idx < KK * 64) {
        int c = idx & 63, kk = idx >> 6;
        g_ws[dst_off + kk * 64 + c] = w[c * KK + kk];
    }
}

// ---------------------------------------------------------------------------
// Kernel 1: all weight prep (blocks 0..334) + x -> NHWC fp32 / bf16 hi-lo
// split (blocks 335..1358).
// ---------------------------------------------------------------------------
__global__ __launch_bounds__(256) void prep_split_kernel(
    const float* __restrict__ x,
    const float* cv0_off_w, const float* c0_off_w,
    const float* cvs_off_w, const float* cs_off_w,
    const float* cv0_w, const float* c0_w,
    const float* cvs_w, const float* cs_w)
{
    __shared__ float lds[16 * 68];
    const int bi = blockIdx.x;
    if (bi < 335) {
        if      (bi < 9)   prep_wA_dev(cv0_off_w, AW_A1, 18, 3, 2, bi);
        else if (bi < 59)  prep_wA_dev(c0_off_w,  AW_B1, 50, 5, 4, bi - 9);
        else if (bi < 109) prep_wA_dev(cvs_off_w, AW_A2, 50, 5, 4, bi - 59);
        else if (bi < 305) prep_wA_dev(cs_off_w,  AW_B2, 98, 7, 8, bi - 109);
        else if (bi < 308) prep_dwT_dev(cv0_w, DW_A1, 9,  bi - 305);
        else if (bi < 315) prep_dwT_dev(c0_w,  DW_B1, 25, bi - 308);
        else if (bi < 322) prep_dwT_dev(cvs_w, DW_A2, 25, bi - 315);
        else               prep_dwT_dev(cs_w,  DW_B2, 49, bi - 322);
        return;
    }
    const int s  = bi - 335;
    const int b  = s & 1;
    const int br = (s >> 1) & 1;
    const int p0 = (s >> 2) * 16;
    const float* sb = x + (long)b * (128 * HW) + (long)br * (64 * HW);
    bf_t*  dhi = (bf_t*)(g_ws + (br ? XB_HI : XA_HI));
    bf_t*  dlo = (bf_t*)(g_ws + (br ? XB_LO : XA_LO));
    float* df  = g_ws + (br ? XB_F32 : XA_F32);
    const int t = threadIdx.x;
    {
        const int px = t & 15;
        const int c0 = t >> 4;
#pragma unroll
        for (int pass = 0; pass < 4; ++pass) {
            int ci = c0 + pass * 16;
            lds[px * 68 + ci] = sb[ci * HW + p0 + px];
        }
    }
    __syncthreads();
    if (t < 128) {
        int px = t >> 3, q = t & 7;
        bf8_t vh, vl;
        f4_t  f0, f1;
#pragma unroll
        for (int j = 0; j < 8; ++j) {
            float a = lds[px * 68 + q * 8 + j];
            bf_t hcast = (bf_t)a;
            vh[j] = hcast;
            vl[j] = (bf_t)(a - (float)hcast);
            if (j < 4) f0[j] = a; else f1[j - 4] = a;
        }
        long base = (((long)b * 4096 + p0 + px) * 64) + q * 8;
        *(bf8_t*)&dhi[base] = vh;
        *(bf8_t*)&dlo[base] = vl;
        *(f4_t*)&df[base]     = f0;
        *(f4_t*)&df[base + 4] = f1;
    }
}

// ---------------------------------------------------------------------------
// MFMA implicit-GEMM conv body (hi/lo split input), dynamic-LDS version.
// ---------------------------------------------------------------------------
template<int K, int DIL, int PAD, int NCOT, int CPG>
__device__ __forceinline__ void mfma_conv_dev(
    int bx, int by, bf_t* smem,
    int hi_off, int lo_off, int aw_off, const float* __restrict__ bias,
    int dst_off, int Cout)
{
    constexpr int COLS = 64 + 2 * PAD;
    const bf_t* shi = (const bf_t*)(g_ws + hi_off);
    const bf_t* slo = (const bf_t*)(g_ws + lo_off);
    const bf_t* aw  = (const bf_t*)(g_ws + aw_off);
    float* dst = g_ws + dst_off;
    bf_t* lds0 = smem;
    bf_t* lds1 = smem + COLS * 72;

    const int t    = threadIdx.x;
    const int lane = t & 63;
    const int wv   = t >> 6;
    const int b    = bx >> 6;
    const int h    = bx & 63;
    const int ct0  = by * CPG;

    const int n0 = lane & 15;
    const int kq = lane >> 4;

    f4_t acc[CPG];
#pragma unroll
    for (int i = 0; i < CPG; ++i) acc[i] = (f4_t){0.f, 0.f, 0.f, 0.f};

    for (int ky = 0; ky < K; ++ky) {
        const int ih = h - PAD + ky * DIL;
        __syncthreads();
        if ((unsigned)ih < 64u) {
            const long rowb = ((long)b * 4096 + ih * 64) * 64;
            for (int c = t; c < COLS * 8; c += 256) {
                int col = c >> 3, q = c & 7;
                int iw = col - PAD;
                bf8_t vh, vl;
                if ((unsigned)iw < 64u) {
                    vh = *(const bf8_t*)&shi[rowb + iw * 64 + q * 8];
                    vl = *(const bf8_t*)&slo[rowb + iw * 64 + q * 8];
                } else { vh = bf8_zero(); vl = bf8_zero(); }
                *(bf8_t*)&lds0[col * 72 + q * 8] = vh;
                *(bf8_t*)&lds1[col * 72 + q * 8] = vl;
            }
        } else {
            bf8_t z = bf8_zero();
            for (int c = t; c < COLS * 8; c += 256) {
                int col = c >> 3, q = c & 7;
                *(bf8_t*)&lds0[col * 72 + q * 8] = z;
                *(bf8_t*)&lds1[col * 72 + q * 8] = z;
            }
        }
        __syncthreads();
#pragma unroll
        for (int kx = 0; kx < K; ++kx) {
            const int tap = ky * K + kx;
            bf8_t afr[CPG][2];
#pragma unroll
            for (int ct = 0; ct < CPG; ++ct)
#pragma unroll
                for (int kh = 0; kh < 2; ++kh)
                    afr[ct][kh] = *(const bf8_t*)
                        &aw[((((long)tap * NCOT + ct0 + ct) * 2 + kh) * 64 + lane) * 8];
            const int colb = (wv * 16 + n0 + kx * DIL) * 72;
#pragma unroll
            for (int kh = 0; kh < 2; ++kh) {
                const bf8_t bh = *(const bf8_t*)&lds0[colb + kh * 32 + kq * 8];
                const bf8_t bl = *(const bf8_t*)&lds1[colb + kh * 32 + kq * 8];
#pragma unroll
                for (int ct = 0; ct < CPG; ++ct) {
                    acc[ct] = __builtin_amdgcn_mfma_f32_16x16x32_bf16(
                        afr[ct][kh], bh, acc[ct], 0, 0, 0);
                    acc[ct] = __builtin_amdgcn_mfma_f32_16x16x32_bf16(
                        afr[ct][kh], bl, acc[ct], 0, 0, 0);
                }
            }
        }
    }

    const int w = wv * 16 + n0;
#pragma unroll
    for (int ct = 0; ct < CPG; ++ct) {
#pragma unroll
        for (int r = 0; r < 4; ++r) {
            int co = (ct0 + ct) * 16 + kq * 4 + r;
            if (co < Cout)
                dst[((long)b * Cout + co) * HW + h * 64 + w] = acc[ct][r] + bias[co];
        }
    }
}

// Kernel 2: stage-1 convs, k3 (256 blocks) / k5 (512 blocks) interleaved mod 3.
__global__ __launch_bounds__(256) void conv_s1_kernel(
    const float* __restrict__ biasA, const float* __restrict__ biasB)
{
    extern __shared__ __align__(16) bf_t smem1[];
    const int bi = blockIdx.x;
    const int g = bi / 3, r = bi % 3;
    if (r == 0)
        mfma_conv_dev<3, 1, 1, 2, 1>(g & 127, g >> 7, smem1,
                                     XA_HI, XA_LO, AW_A1, biasA, OFF_A, 18);
    else {
        const int s = 2 * g + (r - 1);
        mfma_conv_dev<5, 1, 2, 4, 1>(s & 127, s >> 7, smem1,
                                     XB_HI, XB_LO, AW_B1, biasB, OFF_B, 50);
    }
}

// Kernel 4: stage-2 convs, k5 / k7 interleaved even/odd. smem 23616 B.
__global__ __launch_bounds__(256) void conv_s2_kernel(
    const float* __restrict__ biasA, const float* __restrict__ biasB)
{
    extern __shared__ __align__(16) bf_t smem2[];
    const int bi = blockIdx.x;
    const int s = bi >> 1;
    if ((bi & 1) == 0)
        mfma_conv_dev<5, 3, 6, 4, 1>(s & 127, s >> 7, smem2,
                                     A1_HI, A1_LO, AW_A2, biasA, OFF_A, 50);
    else
        mfma_conv_dev<7, 3, 9, 8, 2>(s & 127, s >> 7, smem2,
                                     B1_HI, B1_LO, AW_B2, biasB, OFF_B, 98);
}

// ---------------------------------------------------------------------------
// Fused deformable sampler, pair-load + 2-pixels-per-wave edition.
//
// Round-3/4 counters: latency-bound (VALUBusy ~14%, hbm 2.4%, 28 cy/load
// issued) with ~1.5-2 loads in flight per wave; explicit batching was
// re-serialized by the scheduler (VGPR stayed 32). Fix: give each wave TWO
// pixels -> per tap there are 4 structurally independent gathers (2 rows x
// 2 pixels) that share nothing, so >=4 loads stay in flight regardless of
// scheduling, and the dw LDS read amortizes over both pixels.
//
// Block = 256 threads = 4 waves = 8 pixels; grid halves to 2048.
// Phase A: rec(tap kk, pixel pxl) = [wA, wB, addr, pad] per row (32 B),
// layout recs[(kk*8+pxl)*8 + row*4]. Border clamps folded into wA/wB.
// Phase B: lane j = t&31 owns channels {2j,2j+1}; wave half owns row y0/y1;
// one __shfl_xor(...,32) per pixel combines rows.
// ---------------------------------------------------------------------------
template<int KK, int WRITE_HILO>
__device__ __forceinline__ void sample_fused_dev(
    int bx, float* recs, float* dwl, int src_off, int off_off, int dwt_off,
    int dst_off, int hi_off, int lo_off, int K, int pad, int dil)
{
    const int t   = threadIdx.x;
    const int pgi = ((bx & 7) << 7) | (bx >> 3);   // XCD-contiguous chunks

    // phase A: pair records for this block's 8 pixels
    for (int rec = t; rec < 8 * KK; rec += 256) {
        const int pxl = rec & 7;
        const int kk  = rec >> 3;
        const int pg  = pgi * 8 + pxl;
        const int b   = pg >> 12;
        const int p   = pg & 4095;
        const int h   = p >> 6, w = p & 63;
        const float oy = g_ws[off_off + ((long)(b * 2 * KK + 2 * kk)) * HW + p];
        const float ox = g_ws[off_off + ((long)(b * 2 * KK + 2 * kk + 1)) * HW + p];
        const float py = oy + (float)(h - pad + (kk / K) * dil);
        const float px = ox + (float)(w - pad + (kk % K) * dil);
        const float fy = floorf(py), fx = floorf(px);
        const float ly = py - fy,    lx = px - fx;
        const int y0 = (int)fy, x0 = (int)fx;
        const int y1 = y0 + 1,  x1 = x0 + 1;
        const float ry0 = ((unsigned)y0 < 64u) ? (1.f - ly) : 0.f;
        const float ry1 = ((unsigned)y1 < 64u) ? ly : 0.f;
        const float cx0 = ((unsigned)x0 < 64u) ? (1.f - lx) : 0.f;
        const float cx1 = ((unsigned)x1 < 64u) ? lx : 0.f;
        const int xbase = min(max(x0, 0), 62);
        const float sA = (xbase == x0) ? cx0 : ((xbase == x1) ? cx1 : 0.f);
        const float sB = ((xbase + 1) == x1) ? cx1
                                             : (((xbase + 1) == x0) ? cx0 : 0.f);
        const int y0c = min(max(y0, 0), 63), y1c = min(max(y1, 0), 63);
        const int a0 = (y0c * 64 + xbase) * 256;   // byte address of row-y0 pair
        const int a1 = (y1c * 64 + xbase) * 256;
        float* rp = &recs[rec * 8];
        f4_t r0, r1;
        r0[0] = ry0 * sA; r0[1] = ry0 * sB;
        r0[2] = __int_as_float(a0); r0[3] = 0.f;
        r1[0] = ry1 * sA; r1[1] = ry1 * sB;
        r1[2] = __int_as_float(a1); r1[3] = 0.f;
        *(f4_t*)rp       = r0;
        *(f4_t*)(rp + 4) = r1;
    }

    // depthwise weights -> LDS (coalesced copy, overlaps phase A latency)
    for (int e = t; e < KK * 64; e += 256) dwl[e] = g_ws[dwt_off + e];
    __syncthreads();

    // phase B: wave wv handles pixels {2wv, 2wv+1}
    const int j    = t & 31;         // channel pair {2j, 2j+1}
    const int half = (t >> 5) & 1;   // 0: row y0, 1: row y1
    const int wv   = t >> 6;
    const int px0  = wv * 2, px1 = wv * 2 + 1;
    const int pg0  = pgi * 8 + px0;
    const int b    = pg0 >> 12;      // both pixels share the batch (8-aligned)

    const char*  sb  = (const char*)(g_ws + src_off + ((long)b << 18)) + j * 8;
    const float* dwp = dwl + 2 * j;

    float ax0 = 0.f, ay0 = 0.f, ax1 = 0.f, ay1 = 0.f;
#pragma unroll
    for (int kk = 0; kk < KK; ++kk) {
        const f4_t r0 = *(const f4_t*)&recs[(kk * 8 + px0) * 8 + half * 4];
        const f4_t r1 = *(const f4_t*)&recs[(kk * 8 + px1) * 8 + half * 4];
        const f2_t dw = *(const f2_t*)(dwp + kk * 64);
        const char* ra = sb + __float_as_int(r0[2]);
        const char* rb = sb + __float_as_int(r1[2]);
        const f2_t vA0 = *(const f2_t*)ra;
        const f2_t vB0 = *(const f2_t*)(ra + 256);
        const f2_t vA1 = *(const f2_t*)rb;
        const f2_t vB1 = *(const f2_t*)(rb + 256);
        ax0 = fmaf(dw[0], fmaf(r0[0], vA0[0], r0[1] * vB0[0]), ax0);
        ay0 = fmaf(dw[1], fmaf(r0[0], vA0[1], r0[1] * vB0[1]), ay0);
        ax1 = fmaf(dw[0], fmaf(r1[0], vA1[0], r1[1] * vB1[0]), ax1);
        ay1 = fmaf(dw[1], fmaf(r1[0], vA1[1], r1[1] * vB1[1]), ay1);
    }

    // combine row halves (each half holds its row's full weighted sum)
    ax0 += __shfl_xor(ax0, 32);
    ay0 += __shfl_xor(ay0, 32);
    ax1 += __shfl_xor(ax1, 32);
    ay1 += __shfl_xor(ay1, 32);

    if (half == 0) {
        const int p0 = pg0 & 4095;
        const long ob0 = ((long)b * 4096 + p0) * 64 + 2 * j;
        const long ob1 = ob0 + 64;                 // px1 = px0 + 1 (same batch)
        f2_t o0; o0[0] = ax0; o0[1] = ay0;
        f2_t o1; o1[0] = ax1; o1[1] = ay1;
        *(f2_t*)&g_ws[dst_off + ob0] = o0;
        *(f2_t*)&g_ws[dst_off + ob1] = o1;
        if (WRITE_HILO) {
            bf_t hx0 = (bf_t)ax0, hy0 = (bf_t)ay0;
            bf_t hx1 = (bf_t)ax1, hy1 = (bf_t)ay1;
            bf2_t h0; h0[0] = hx0; h0[1] = hy0;
            bf2_t l0; l0[0] = (bf_t)(ax0 - (float)hx0); l0[1] = (bf_t)(ay0 - (float)hy0);
            bf2_t h1; h1[0] = hx1; h1[1] = hy1;
            bf2_t l1; l1[0] = (bf_t)(ax1 - (float)hx1); l1[1] = (bf_t)(ay1 - (float)hy1);
            *(bf2_t*)&((bf_t*)(g_ws + hi_off))[ob0] = h0;
            *(bf2_t*)&((bf_t*)(g_ws + lo_off))[ob0] = l0;
            *(bf2_t*)&((bf_t*)(g_ws + hi_off))[ob1] = h1;
            *(bf2_t*)&((bf_t*)(g_ws + lo_off))[ob1] = l1;
        }
    }
}

template<int KA, int KB, int WRITE_HILO>
__global__ __launch_bounds__(256) void sample_kernel(
    int srcA, int offA, int dwtA, int dstA, int hiA, int loA, int padA, int dilA,
    int srcB, int offB, int dwtB, int dstB, int hiB, int loB, int padB, int dilB)
{
    constexpr int KKmax = KB * KB;
    __shared__ __align__(16) float recs[8 * KKmax * 8];
    __shared__ __align__(16) float dwl[KKmax * 64];
    const int bx = blockIdx.x;
    const int s = bx >> 1;
    if ((bx & 1) == 0)       // interleaved: flattens A/B duration imbalance
        sample_fused_dev<KA * KA, WRITE_HILO>(s, recs, dwl, srcA, offA, dwtA,
                                              dstA, hiA, loA, KA, padA, dilA);
    else
        sample_fused_dev<KB * KB, WRITE_HILO>(s, recs, dwl, srcB, offB, dwtB,
                                              dstB, hiB, loB, KB, padB, dilB);
}

// ---------------------------------------------------------------------------
// Kernel 6: per-branch 1x1 conv (+bias), then out = x * result.
// ---------------------------------------------------------------------------
__global__ __launch_bounds__(256) void final_kernel(
    const float* __restrict__ x,
    int aA_off, int aB_off,
    const float* __restrict__ w1, const float* __restrict__ b1,
    const float* __restrict__ w2, const float* __restrict__ b2,
    float* __restrict__ out)
{
    __shared__ float atile[64 * 65];
    __shared__ float wlds[64 * 32];
    const int t  = threadIdx.x;
    const int p0 = blockIdx.x * 64;
    const int by = blockIdx.y;
    const int b  = blockIdx.z;
    const bool brB  = (by >> 1) != 0;
    const int  cbase = (by & 1) * 32;
    const float* a  = g_ws + (brB ? aB_off : aA_off) + (long)b * (4096 * 64);
    const float* wg = brB ? w2 : w1;
    const float* bg = brB ? b2 : b1;

    {
        const int ci = t & 63;
        const int pxg = (t >> 6) * 16;
#pragma unroll
        for (int i = 0; i < 16; ++i) {
            int px = pxg + i;
            atile[px * 65 + ci] = a[(long)(p0 + px) * 64 + ci];
        }
    }
    for (int e = t; e < 2048; e += 256) {
        int col = e & 31, ci = e >> 5;
        wlds[ci * 32 + col] = wg[(cbase + col) * 64 + ci];
    }
    __syncthreads();

    const int px  = t & 63;
    const int cog = t >> 6;
    float acc[8] = {0, 0, 0, 0, 0, 0, 0, 0};
    for (int ci = 0; ci < 64; ++ci) {
        const float av = atile[px * 65 + ci];
        const float* wr = &wlds[ci * 32 + cog * 8];
#pragma unroll
        for (int j = 0; j < 8; ++j) acc[j] = fmaf(av, wr[j], acc[j]);
    }

    const int p = p0 + px;
#pragma unroll
    for (int j = 0; j < 8; ++j) {
        const int co = cbase + cog * 8 + j;
        const int cg = (brB ? 64 : 0) + co;
        const long o = ((long)b * 128 + cg) * HW + p;
        out[o] = (acc[j] + bg[co]) * x[o];
    }
}

// ---------------------------------------------------------------------------
extern "C" void kernel_launch(void* const* d_in, const int* in_sizes, int n_in,
                              void* d_out, int out_size, void* d_ws, size_t ws_size,
                              hipStream_t stream) {
    const float* x         = (const float*)d_in[0];
    const float* cv0_off_w = (const float*)d_in[1];
    const float* cv0_off_b = (const float*)d_in[2];
    const float* cv0_w     = (const float*)d_in[3];
    const float* cvs_off_w = (const float*)d_in[4];
    const float* cvs_off_b = (const float*)d_in[5];
    const float* cvs_w     = (const float*)d_in[6];
    const float* c0_off_w  = (const float*)d_in[7];
    const float* c0_off_b  = (const float*)d_in[8];
    const float* c0_w      = (const float*)d_in[9];
    const float* cs_off_w  = (const float*)d_in[10];
    const float* cs_off_b  = (const float*)d_in[11];
    const float* cs_w      = (const float*)d_in[12];
    const float* conv1_w   = (const float*)d_in[13];
    const float* conv1_b   = (const float*)d_in[14];
    const float* conv2_w   = (const float*)d_in[15];
    const float* conv2_b   = (const float*)d_in[16];
    float* out = (float*)d_out;
    (void)d_ws; (void)ws_size;

    // 1: weight prep + x NHWC/hi-lo split
    prep_split_kernel<<<dim3(1359), 256, 0, stream>>>(
        x, cv0_off_w, c0_off_w, cvs_off_w, cs_off_w, cv0_w, c0_w, cvs_w, cs_w);

    // 2: stage-1 offset convs (k3 + k5, interleaved)
    conv_s1_kernel<<<dim3(768), 256, 19584, stream>>>(cv0_off_b, c0_off_b);

    // 3: stage-1 fused precompute+sampling (+ hi/lo emit)
    sample_kernel<3, 5, 1><<<dim3(2048), 256, 0, stream>>>(
        XA_F32, OFF_A, DW_A1, A1_F32, A1_HI, A1_LO, 1, 1,
        XB_F32, OFF_B, DW_B1, B1_F32, B1_HI, B1_LO, 2, 1);

    // 4: stage-2 offset convs (k5 + k7, interleaved)
    conv_s2_kernel<<<dim3(1024), 256, 23616, stream>>>(cvs_off_b, cs_off_b);

    // 5: stage-2 fused precompute+sampling
    sample_kernel<5, 7, 0><<<dim3(2048), 256, 0, stream>>>(
        A1_F32, OFF_A, DW_A2, A2_F32, 0, 0, 6, 3,
        B1_F32, OFF_B, DW_B2, B2_F32, 0, 0, 9, 3);

    // 6: 1x1 convs + gating multiply
    final_kernel<<<dim3(64, 4, 2), 256, 0, stream>>>(
        x, A2_F32, B2_F32, conv1_w, conv1_b, conv2_w, conv2_b, out);
}

// Round 6
// 209.793 us; speedup vs baseline: 1.0825x; 1.0825x over previous
//
#include <hip/hip_runtime.h>
#include <hip/hip_bf16.h>

#define HW   4096

typedef __bf16 bf_t;
typedef __bf16 bf8_t __attribute__((ext_vector_type(8)));
typedef __bf16 bf2_t __attribute__((ext_vector_type(2)));
typedef __bf16 bf4v_t __attribute__((ext_vector_type(4)));
typedef float  f4_t  __attribute__((ext_vector_type(4)));
typedef float  f2_t  __attribute__((ext_vector_type(2)));
typedef int    i4_t  __attribute__((ext_vector_type(4)));

// Static device workspace (element offsets into g_ws, in floats):
#define OFF_A    0              // 2*50*HW NCHW offset maps
#define OFF_B    409600         // 2*98*HW
#define A1_F32   1212416        // NHWC fp32 [b][4096][64] = 524288 each
#define B1_F32   1736704
#define A2_F32   2260992
#define B2_F32   2785280
#define XA_F32   3309568
#define XB_F32   3833856
#define XA_HI    4358144        // bf16 NHWC = 262144 floats each
#define XA_LO    4620288
#define XB_HI    4882432
#define XB_LO    5144576
#define A1_HI    5406720
#define A1_LO    5668864
#define B1_HI    5931008
#define B1_LO    6193152
#define AW_A1    6455296        // conv weight packs (bf16 A-frag)
#define AW_B1    6464512
#define AW_A2    6515712
#define AW_B2    6566912
#define DW_A1    6767616        // depthwise weights transposed [KK][64]
#define DW_B1    6768192
#define DW_A2    6769792
#define DW_B2    6771392
#define WS_TOT   6774528

__device__ __align__(16) float g_ws[WS_TOT];

__device__ __forceinline__ bf8_t bf8_zero() {
    bf8_t v;
#pragma unroll
    for (int j = 0; j < 8; ++j) v[j] = (bf_t)0.f;
    return v;
}

// ---------------------------------------------------------------------------
// Weight prep helpers (range-dispatched).
// ---------------------------------------------------------------------------
__device__ __forceinline__ void prep_wA_dev(const float* wg, int aw_off,
                                            int Cout, int K, int NCOT, int lb) {
    const int KK = K * K;
    const int total = KK * NCOT * 128;
    const int idx = lb * 256 + threadIdx.x;
    if (idx >= total) return;
    bf_t* aw = (bf_t*)(g_ws + aw_off);
    int lane = idx & 63;
    int kh   = (idx >> 6) & 1;
    int cot  = (idx >> 7) % NCOT;
    int tap  = idx / (128 * NCOT);
    int co   = cot * 16 + (lane & 15);
    int ci0  = kh * 32 + (lane >> 4) * 8;
    bf8_t v;
#pragma unroll
    for (int j = 0; j < 8; ++j) {
        float f = (co < Cout) ? wg[(co * 64 + ci0 + j) * KK + tap] : 0.f;
        v[j] = (bf_t)f;
    }
    *(bf8_t*)&aw[(long)idx * 8] = v;
}

__device__ __forceinline__ void prep_dwT_dev(const float* w, int dst_off,
                                             int KK, int lb) {
    const int idx = lb * 256 + threadIdx.x;
    if (idx < KK * 64) {
        int c = idx & 63, kk = idx >> 6;
        g_ws[dst_off + kk * 64 + c] = w[c * KK + kk];
    }
}

// ---------------------------------------------------------------------------
// Kernel 1: all weight prep (blocks 0..334) + x -> NHWC fp32 / bf16 hi-lo
// split (blocks 335..1358).
// ---------------------------------------------------------------------------
__global__ __launch_bounds__(256) void prep_split_kernel(
    const float* __restrict__ x,
    const float* cv0_off_w, const float* c0_off_w,
    const float* cvs_off_w, const float* cs_off_w,
    const float* cv0_w, const float* c0_w,
    const float* cvs_w, const float* cs_w)
{
    __shared__ float lds[16 * 68];
    const int bi = blockIdx.x;
    if (bi < 335) {
        if      (bi < 9)   prep_wA_dev(cv0_off_w, AW_A1, 18, 3, 2, bi);
        else if (bi < 59)  prep_wA_dev(c0_off_w,  AW_B1, 50, 5, 4, bi - 9);
        else if (bi < 109) prep_wA_dev(cvs_off_w, AW_A2, 50, 5, 4, bi - 59);
        else if (bi < 305) prep_wA_dev(cs_off_w,  AW_B2, 98, 7, 8, bi - 109);
        else if (bi < 308) prep_dwT_dev(cv0_w, DW_A1, 9,  bi - 305);
        else if (bi < 315) prep_dwT_dev(c0_w,  DW_B1, 25, bi - 308);
        else if (bi < 322) prep_dwT_dev(cvs_w, DW_A2, 25, bi - 315);
        else               prep_dwT_dev(cs_w,  DW_B2, 49, bi - 322);
        return;
    }
    const int s  = bi - 335;
    const int b  = s & 1;
    const int br = (s >> 1) & 1;
    const int p0 = (s >> 2) * 16;
    const float* sb = x + (long)b * (128 * HW) + (long)br * (64 * HW);
    bf_t*  dhi = (bf_t*)(g_ws + (br ? XB_HI : XA_HI));
    bf_t*  dlo = (bf_t*)(g_ws + (br ? XB_LO : XA_LO));
    float* df  = g_ws + (br ? XB_F32 : XA_F32);
    const int t = threadIdx.x;
    {
        const int px = t & 15;
        const int c0 = t >> 4;
#pragma unroll
        for (int pass = 0; pass < 4; ++pass) {
            int ci = c0 + pass * 16;
            lds[px * 68 + ci] = sb[ci * HW + p0 + px];
        }
    }
    __syncthreads();
    if (t < 128) {
        int px = t >> 3, q = t & 7;
        bf8_t vh, vl;
        f4_t  f0, f1;
#pragma unroll
        for (int j = 0; j < 8; ++j) {
            float a = lds[px * 68 + q * 8 + j];
            bf_t hcast = (bf_t)a;
            vh[j] = hcast;
            vl[j] = (bf_t)(a - (float)hcast);
            if (j < 4) f0[j] = a; else f1[j - 4] = a;
        }
        long base = (((long)b * 4096 + p0 + px) * 64) + q * 8;
        *(bf8_t*)&dhi[base] = vh;
        *(bf8_t*)&dlo[base] = vl;
        *(f4_t*)&df[base]     = f0;
        *(f4_t*)&df[base + 4] = f1;
    }
}

// ---------------------------------------------------------------------------
// MFMA implicit-GEMM conv body (hi/lo split input), dynamic-LDS version.
// ---------------------------------------------------------------------------
template<int K, int DIL, int PAD, int NCOT, int CPG>
__device__ __forceinline__ void mfma_conv_dev(
    int bx, int by, bf_t* smem,
    int hi_off, int lo_off, int aw_off, const float* __restrict__ bias,
    int dst_off, int Cout)
{
    constexpr int COLS = 64 + 2 * PAD;
    const bf_t* shi = (const bf_t*)(g_ws + hi_off);
    const bf_t* slo = (const bf_t*)(g_ws + lo_off);
    const bf_t* aw  = (const bf_t*)(g_ws + aw_off);
    float* dst = g_ws + dst_off;
    bf_t* lds0 = smem;
    bf_t* lds1 = smem + COLS * 72;

    const int t    = threadIdx.x;
    const int lane = t & 63;
    const int wv   = t >> 6;
    const int b    = bx >> 6;
    const int h    = bx & 63;
    const int ct0  = by * CPG;

    const int n0 = lane & 15;
    const int kq = lane >> 4;

    f4_t acc[CPG];
#pragma unroll
    for (int i = 0; i < CPG; ++i) acc[i] = (f4_t){0.f, 0.f, 0.f, 0.f};

    for (int ky = 0; ky < K; ++ky) {
        const int ih = h - PAD + ky * DIL;
        __syncthreads();
        if ((unsigned)ih < 64u) {
            const long rowb = ((long)b * 4096 + ih * 64) * 64;
            for (int c = t; c < COLS * 8; c += 256) {
                int col = c >> 3, q = c & 7;
                int iw = col - PAD;
                bf8_t vh, vl;
                if ((unsigned)iw < 64u) {
                    vh = *(const bf8_t*)&shi[rowb + iw * 64 + q * 8];
                    vl = *(const bf8_t*)&slo[rowb + iw * 64 + q * 8];
                } else { vh = bf8_zero(); vl = bf8_zero(); }
                *(bf8_t*)&lds0[col * 72 + q * 8] = vh;
                *(bf8_t*)&lds1[col * 72 + q * 8] = vl;
            }
        } else {
            bf8_t z = bf8_zero();
            for (int c = t; c < COLS * 8; c += 256) {
                int col = c >> 3, q = c & 7;
                *(bf8_t*)&lds0[col * 72 + q * 8] = z;
                *(bf8_t*)&lds1[col * 72 + q * 8] = z;
            }
        }
        __syncthreads();
#pragma unroll
        for (int kx = 0; kx < K; ++kx) {
            const int tap = ky * K + kx;
            bf8_t afr[CPG][2];
#pragma unroll
            for (int ct = 0; ct < CPG; ++ct)
#pragma unroll
                for (int kh = 0; kh < 2; ++kh)
                    afr[ct][kh] = *(const bf8_t*)
                        &aw[((((long)tap * NCOT + ct0 + ct) * 2 + kh) * 64 + lane) * 8];
            const int colb = (wv * 16 + n0 + kx * DIL) * 72;
#pragma unroll
            for (int kh = 0; kh < 2; ++kh) {
                const bf8_t bh = *(const bf8_t*)&lds0[colb + kh * 32 + kq * 8];
                const bf8_t bl = *(const bf8_t*)&lds1[colb + kh * 32 + kq * 8];
#pragma unroll
                for (int ct = 0; ct < CPG; ++ct) {
                    acc[ct] = __builtin_amdgcn_mfma_f32_16x16x32_bf16(
                        afr[ct][kh], bh, acc[ct], 0, 0, 0);
                    acc[ct] = __builtin_amdgcn_mfma_f32_16x16x32_bf16(
                        afr[ct][kh], bl, acc[ct], 0, 0, 0);
                }
            }
        }
    }

    const int w = wv * 16 + n0;
#pragma unroll
    for (int ct = 0; ct < CPG; ++ct) {
#pragma unroll
        for (int r = 0; r < 4; ++r) {
            int co = (ct0 + ct) * 16 + kq * 4 + r;
            if (co < Cout)
                dst[((long)b * Cout + co) * HW + h * 64 + w] = acc[ct][r] + bias[co];
        }
    }
}

// Kernel 2: stage-1 convs, k3 (256 blocks) / k5 (512 blocks) interleaved mod 3.
__global__ __launch_bounds__(256) void conv_s1_kernel(
    const float* __restrict__ biasA, const float* __restrict__ biasB)
{
    extern __shared__ __align__(16) bf_t smem1[];
    const int bi = blockIdx.x;
    const int g = bi / 3, r = bi % 3;
    if (r == 0)
        mfma_conv_dev<3, 1, 1, 2, 1>(g & 127, g >> 7, smem1,
                                     XA_HI, XA_LO, AW_A1, biasA, OFF_A, 18);
    else {
        const int s = 2 * g + (r - 1);
        mfma_conv_dev<5, 1, 2, 4, 1>(s & 127, s >> 7, smem1,
                                     XB_HI, XB_LO, AW_B1, biasB, OFF_B, 50);
    }
}

// Kernel 4: stage-2 convs, k5 / k7 interleaved even/odd. smem 23616 B.
__global__ __launch_bounds__(256) void conv_s2_kernel(
    const float* __restrict__ biasA, const float* __restrict__ biasB)
{
    extern __shared__ __align__(16) bf_t smem2[];
    const int bi = blockIdx.x;
    const int s = bi >> 1;
    if ((bi & 1) == 0)
        mfma_conv_dev<5, 3, 6, 4, 1>(s & 127, s >> 7, smem2,
                                     A1_HI, A1_LO, AW_A2, biasA, OFF_A, 50);
    else
        mfma_conv_dev<7, 3, 9, 8, 2>(s & 127, s >> 7, smem2,
                                     B1_HI, B1_LO, AW_B2, biasB, OFF_B, 98);
}

// ---------------------------------------------------------------------------
// Fused deformable sampler, single-dwordx4-per-gather edition.
//
// R4/R5 counters: duration invariant to waves x per-wave chains at 1.21M
// VMEM instrs (= 28 cy/instr/CU). Hypothesis H1: per-CU VMEM instruction
// throughput cap for scattered 8-line loads. Test: halve instruction count
// at IDENTICAL line traffic by widening each gather to one dwordx4 covering
// the whole 512 B (row, col-pair) span.
//
// Lane mapping (64 lanes): half = lane>>5 -> row y0/y1; sub = (lane>>4)&1 ->
// col A/B of the pair; q = lane&15 -> channel quad (ch 4q..4q+3). Per
// (px,tap): ONE global dwordx4; each lane accumulates only its column's
// weighted partial (weight chosen by sub, no per-tap shuffle). Column+row
// combine = 8 __shfl_xor once per PIXEL at the end.
//
// Phase A unchanged: rec = [wA, wB, addr, pad] per (tap, px, row); border
// clamps folded into wA/wB; addr 256B-aligned pair base.
// ---------------------------------------------------------------------------
template<int KK, int WRITE_HILO>
__device__ __forceinline__ void sample_fused_dev(
    int bx, float* recs, float* dwl, int src_off, int off_off, int dwt_off,
    int dst_off, int hi_off, int lo_off, int K, int pad, int dil)
{
    const int t   = threadIdx.x;
    const int pgi = ((bx & 7) << 7) | (bx >> 3);   // XCD-contiguous chunks

    // phase A: pair records for this block's 8 pixels
    for (int rec = t; rec < 8 * KK; rec += 256) {
        const int pxl = rec & 7;
        const int kk  = rec >> 3;
        const int pg  = pgi * 8 + pxl;
        const int b   = pg >> 12;
        const int p   = pg & 4095;
        const int h   = p >> 6, w = p & 63;
        const float oy = g_ws[off_off + ((long)(b * 2 * KK + 2 * kk)) * HW + p];
        const float ox = g_ws[off_off + ((long)(b * 2 * KK + 2 * kk + 1)) * HW + p];
        const float py = oy + (float)(h - pad + (kk / K) * dil);
        const float px = ox + (float)(w - pad + (kk % K) * dil);
        const float fy = floorf(py), fx = floorf(px);
        const float ly = py - fy,    lx = px - fx;
        const int y0 = (int)fy, x0 = (int)fx;
        const int y1 = y0 + 1,  x1 = x0 + 1;
        const float ry0 = ((unsigned)y0 < 64u) ? (1.f - ly) : 0.f;
        const float ry1 = ((unsigned)y1 < 64u) ? ly : 0.f;
        const float cx0 = ((unsigned)x0 < 64u) ? (1.f - lx) : 0.f;
        const float cx1 = ((unsigned)x1 < 64u) ? lx : 0.f;
        const int xbase = min(max(x0, 0), 62);
        const float sA = (xbase == x0) ? cx0 : ((xbase == x1) ? cx1 : 0.f);
        const float sB = ((xbase + 1) == x1) ? cx1
                                             : (((xbase + 1) == x0) ? cx0 : 0.f);
        const int y0c = min(max(y0, 0), 63), y1c = min(max(y1, 0), 63);
        const int a0 = (y0c * 64 + xbase) * 256;   // byte address of row-y0 pair
        const int a1 = (y1c * 64 + xbase) * 256;
        float* rp = &recs[rec * 8];
        f4_t r0, r1;
        r0[0] = ry0 * sA; r0[1] = ry0 * sB;
        r0[2] = __int_as_float(a0); r0[3] = 0.f;
        r1[0] = ry1 * sA; r1[1] = ry1 * sB;
        r1[2] = __int_as_float(a1); r1[3] = 0.f;
        *(f4_t*)rp       = r0;
        *(f4_t*)(rp + 4) = r1;
    }

    // depthwise weights -> LDS (coalesced copy, overlaps phase A latency)
    for (int e = t; e < KK * 64; e += 256) dwl[e] = g_ws[dwt_off + e];
    __syncthreads();

    // phase B: wave wv handles pixels {2wv, 2wv+1}
    const int lane = t & 63;
    const int half = (lane >> 5) & 1;  // row select
    const int sub  = (lane >> 4) & 1;  // col slot within the pair
    const int q    = lane & 15;        // channel quad (ch 4q..4q+3)
    const int wv   = t >> 6;
    const int px0  = wv * 2, px1 = wv * 2 + 1;
    const int pg0  = pgi * 8 + px0;
    const int b    = pg0 >> 12;        // both pixels share the batch (8-aligned)

    const char*  sbl = (const char*)(g_ws + src_off + ((long)b << 18))
                       + sub * 256 + q * 16;
    const float* dwp = dwl + q * 4;

    f4_t acc0 = {0.f, 0.f, 0.f, 0.f};
    f4_t acc1 = {0.f, 0.f, 0.f, 0.f};
#pragma unroll
    for (int kk = 0; kk < KK; ++kk) {
        const f4_t r0 = *(const f4_t*)&recs[(kk * 8 + px0) * 8 + half * 4];
        const f4_t r1 = *(const f4_t*)&recs[(kk * 8 + px1) * 8 + half * 4];
        const f4_t dw = *(const f4_t*)(dwp + kk * 64);
        const float w0 = sub ? r0[1] : r0[0];
        const float w1 = sub ? r1[1] : r1[0];
        const f4_t v0 = *(const f4_t*)(sbl + __float_as_int(r0[2]));
        const f4_t v1 = *(const f4_t*)(sbl + __float_as_int(r1[2]));
#pragma unroll
        for (int c = 0; c < 4; ++c) {
            acc0[c] = fmaf(dw[c] * w0, v0[c], acc0[c]);
            acc1[c] = fmaf(dw[c] * w1, v1[c], acc1[c]);
        }
    }

    // combine col slots (xor 16) then rows (xor 32); all lanes end duplicated
#pragma unroll
    for (int c = 0; c < 4; ++c) {
        acc0[c] += __shfl_xor(acc0[c], 16);
        acc0[c] += __shfl_xor(acc0[c], 32);
        acc1[c] += __shfl_xor(acc1[c], 16);
        acc1[c] += __shfl_xor(acc1[c], 32);
    }

    if (lane < 16) {
        const int p0 = pg0 & 4095;
        const long ob0 = ((long)b * 4096 + p0) * 64 + q * 4;
        const long ob1 = ob0 + 64;                 // px1 = px0 + 1 (same batch)
        *(f4_t*)&g_ws[dst_off + ob0] = acc0;
        *(f4_t*)&g_ws[dst_off + ob1] = acc1;
        if (WRITE_HILO) {
            bf4v_t h0, l0, h1, l1;
#pragma unroll
            for (int c = 0; c < 4; ++c) {
                bf_t hh0 = (bf_t)acc0[c]; h0[c] = hh0; l0[c] = (bf_t)(acc0[c] - (float)hh0);
                bf_t hh1 = (bf_t)acc1[c]; h1[c] = hh1; l1[c] = (bf_t)(acc1[c] - (float)hh1);
            }
            *(bf4v_t*)&((bf_t*)(g_ws + hi_off))[ob0] = h0;
            *(bf4v_t*)&((bf_t*)(g_ws + lo_off))[ob0] = l0;
            *(bf4v_t*)&((bf_t*)(g_ws + hi_off))[ob1] = h1;
            *(bf4v_t*)&((bf_t*)(g_ws + lo_off))[ob1] = l1;
        }
    }
}

template<int KA, int KB, int WRITE_HILO>
__global__ __launch_bounds__(256) void sample_kernel(
    int srcA, int offA, int dwtA, int dstA, int hiA, int loA, int padA, int dilA,
    int srcB, int offB, int dwtB, int dstB, int hiB, int loB, int padB, int dilB)
{
    constexpr int KKmax = KB * KB;
    __shared__ __align__(16) float recs[8 * KKmax * 8];
    __shared__ __align__(16) float dwl[KKmax * 64];
    const int bx = blockIdx.x;
    const int s = bx >> 1;
    if ((bx & 1) == 0)       // interleaved: flattens A/B duration imbalance
        sample_fused_dev<KA * KA, WRITE_HILO>(s, recs, dwl, srcA, offA, dwtA,
                                              dstA, hiA, loA, KA, padA, dilA);
    else
        sample_fused_dev<KB * KB, WRITE_HILO>(s, recs, dwl, srcB, offB, dwtB,
                                              dstB, hiB, loB, KB, padB, dilB);
}

// ---------------------------------------------------------------------------
// Kernel 6: per-branch 1x1 conv (+bias), then out = x * result.
// ---------------------------------------------------------------------------
__global__ __launch_bounds__(256) void final_kernel(
    const float* __restrict__ x,
    int aA_off, int aB_off,
    const float* __restrict__ w1, const float* __restrict__ b1,
    const float* __restrict__ w2, const float* __restrict__ b2,
    float* __restrict__ out)
{
    __shared__ float atile[64 * 65];
    __shared__ float wlds[64 * 32];
    const int t  = threadIdx.x;
    const int p0 = blockIdx.x * 64;
    const int by = blockIdx.y;
    const int b  = blockIdx.z;
    const bool brB  = (by >> 1) != 0;
    const int  cbase = (by & 1) * 32;
    const float* a  = g_ws + (brB ? aB_off : aA_off) + (long)b * (4096 * 64);
    const float* wg = brB ? w2 : w1;
    const float* bg = brB ? b2 : b1;

    {
        const int ci = t & 63;
        const int pxg = (t >> 6) * 16;
#pragma unroll
        for (int i = 0; i < 16; ++i) {
            int px = pxg + i;
            atile[px * 65 + ci] = a[(long)(p0 + px) * 64 + ci];
        }
    }
    for (int e = t; e < 2048; e += 256) {
        int col = e & 31, ci = e >> 5;
        wlds[ci * 32 + col] = wg[(cbase + col) * 64 + ci];
    }
    __syncthreads();

    const int px  = t & 63;
    const int cog = t >> 6;
    float acc[8] = {0, 0, 0, 0, 0, 0, 0, 0};
    for (int ci = 0; ci < 64; ++ci) {
        const float av = atile[px * 65 + ci];
        const float* wr = &wlds[ci * 32 + cog * 8];
#pragma unroll
        for (int j = 0; j < 8; ++j) acc[j] = fmaf(av, wr[j], acc[j]);
    }

    const int p = p0 + px;
#pragma unroll
    for (int j = 0; j < 8; ++j) {
        const int co = cbase + cog * 8 + j;
        const int cg = (brB ? 64 : 0) + co;
        const long o = ((long)b * 128 + cg) * HW + p;
        out[o] = (acc[j] + bg[co]) * x[o];
    }
}

// ---------------------------------------------------------------------------
extern "C" void kernel_launch(void* const* d_in, const int* in_sizes, int n_in,
                              void* d_out, int out_size, void* d_ws, size_t ws_size,
                              hipStream_t stream) {
    const float* x         = (const float*)d_in[0];
    const float* cv0_off_w = (const float*)d_in[1];
    const float* cv0_off_b = (const float*)d_in[2];
    const float* cv0_w     = (const float*)d_in[3];
    const float* cvs_off_w = (const float*)d_in[4];
    const float* cvs_off_b = (const float*)d_in[5];
    const float* cvs_w     = (const float*)d_in[6];
    const float* c0_off_w  = (const float*)d_in[7];
    const float* c0_off_b  = (const float*)d_in[8];
    const float* c0_w      = (const float*)d_in[9];
    const float* cs_off_w  = (const float*)d_in[10];
    const float* cs_off_b  = (const float*)d_in[11];
    const float* cs_w      = (const float*)d_in[12];
    const float* conv1_w   = (const float*)d_in[13];
    const float* conv1_b   = (const float*)d_in[14];
    const float* conv2_w   = (const float*)d_in[15];
    const float* conv2_b   = (const float*)d_in[16];
    float* out = (float*)d_out;
    (void)d_ws; (void)ws_size;

    // 1: weight prep + x NHWC/hi-lo split
    prep_split_kernel<<<dim3(1359), 256, 0, stream>>>(
        x, cv0_off_w, c0_off_w, cvs_off_w, cs_off_w, cv0_w, c0_w, cvs_w, cs_w);

    // 2: stage-1 offset convs (k3 + k5, interleaved)
    conv_s1_kernel<<<dim3(768), 256, 19584, stream>>>(cv0_off_b, c0_off_b);

    // 3: stage-1 fused precompute+sampling (+ hi/lo emit)
    sample_kernel<3, 5, 1><<<dim3(2048), 256, 0, stream>>>(
        XA_F32, OFF_A, DW_A1, A1_F32, A1_HI, A1_LO, 1, 1,
        XB_F32, OFF_B, DW_B1, B1_F32, B1_HI, B1_LO, 2, 1);

    // 4: stage-2 offset convs (k5 + k7, interleaved)
    conv_s2_kernel<<<dim3(1024), 256, 23616, stream>>>(cvs_off_b, cs_off_b);

    // 5: stage-2 fused precompute+sampling
    sample_kernel<5, 7, 0><<<dim3(2048), 256, 0, stream>>>(
        A1_F32, OFF_A, DW_A2, A2_F32, 0, 0, 6, 3,
        B1_F32, OFF_B, DW_B2, B2_F32, 0, 0, 9, 3);

    // 6: 1x1 convs + gating multiply
    final_kernel<<<dim3(64, 4, 2), 256, 0, stream>>>(
        x, A2_F32, B2_F32, conv1_w, conv1_b, conv2_w, conv2_b, out);
}

// Round 7
// 204.733 us; speedup vs baseline: 1.1092x; 1.0247x over previous
//
#include <hip/hip_runtime.h>
#include <hip/hip_bf16.h>

#define HW   4096

typedef __bf16 bf_t;
typedef __bf16 bf8_t __attribute__((ext_vector_type(8)));
typedef __bf16 bf2_t __attribute__((ext_vector_type(2)));
typedef __bf16 bf4v_t __attribute__((ext_vector_type(4)));
typedef float  f4_t  __attribute__((ext_vector_type(4)));
typedef float  f2_t  __attribute__((ext_vector_type(2)));
typedef int    i4_t  __attribute__((ext_vector_type(4)));

// Static device workspace (element offsets into g_ws, in floats):
#define OFF_A    0              // 2*50*HW NCHW offset maps
#define OFF_B    409600         // 2*98*HW
#define A1_F32   1212416        // NHWC fp32 [b][4096][64] = 524288 each
#define B1_F32   1736704
#define A2_F32   2260992
#define B2_F32   2785280
#define XA_F32   3309568
#define XB_F32   3833856
#define XA_HI    4358144        // bf16 NHWC = 262144 floats each
#define XA_LO    4620288
#define XB_HI    4882432
#define XB_LO    5144576
#define A1_HI    5406720
#define A1_LO    5668864
#define B1_HI    5931008
#define B1_LO    6193152
#define AW_A1    6455296        // conv weight packs (bf16 A-frag)
#define AW_B1    6464512
#define AW_A2    6515712
#define AW_B2    6566912
#define DW_A1    6767616        // depthwise weights transposed [KK][64]
#define DW_B1    6768192
#define DW_A2    6769792
#define DW_B2    6771392
#define WS_TOT   6774528

__device__ __align__(16) float g_ws[WS_TOT];

__device__ __forceinline__ bf8_t bf8_zero() {
    bf8_t v;
#pragma unroll
    for (int j = 0; j < 8; ++j) v[j] = (bf_t)0.f;
    return v;
}

// ---------------------------------------------------------------------------
// Weight prep helpers (range-dispatched).
// ---------------------------------------------------------------------------
__device__ __forceinline__ void prep_wA_dev(const float* wg, int aw_off,
                                            int Cout, int K, int NCOT, int lb) {
    const int KK = K * K;
    const int total = KK * NCOT * 128;
    const int idx = lb * 256 + threadIdx.x;
    if (idx >= total) return;
    bf_t* aw = (bf_t*)(g_ws + aw_off);
    int lane = idx & 63;
    int kh   = (idx >> 6) & 1;
    int cot  = (idx >> 7) % NCOT;
    int tap  = idx / (128 * NCOT);
    int co   = cot * 16 + (lane & 15);
    int ci0  = kh * 32 + (lane >> 4) * 8;
    bf8_t v;
#pragma unroll
    for (int j = 0; j < 8; ++j) {
        float f = (co < Cout) ? wg[(co * 64 + ci0 + j) * KK + tap] : 0.f;
        v[j] = (bf_t)f;
    }
    *(bf8_t*)&aw[(long)idx * 8] = v;
}

__device__ __forceinline__ void prep_dwT_dev(const float* w, int dst_off,
                                             int KK, int lb) {
    const int idx = lb * 256 + threadIdx.x;
    if (idx < KK * 64) {
        int c = idx & 63, kk = idx >> 6;
        g_ws[dst_off + kk * 64 + c] = w[c * KK + kk];
    }
}

// ---------------------------------------------------------------------------
// Kernel 1: all weight prep (blocks 0..334) + x -> NHWC fp32 / bf16 hi-lo
// split (blocks 335..1358).
// ---------------------------------------------------------------------------
__global__ __launch_bounds__(256) void prep_split_kernel(
    const float* __restrict__ x,
    const float* cv0_off_w, const float* c0_off_w,
    const float* cvs_off_w, const float* cs_off_w,
    const float* cv0_w, const float* c0_w,
    const float* cvs_w, const float* cs_w)
{
    __shared__ float lds[16 * 68];
    const int bi = blockIdx.x;
    if (bi < 335) {
        if      (bi < 9)   prep_wA_dev(cv0_off_w, AW_A1, 18, 3, 2, bi);
        else if (bi < 59)  prep_wA_dev(c0_off_w,  AW_B1, 50, 5, 4, bi - 9);
        else if (bi < 109) prep_wA_dev(cvs_off_w, AW_A2, 50, 5, 4, bi - 59);
        else if (bi < 305) prep_wA_dev(cs_off_w,  AW_B2, 98, 7, 8, bi - 109);
        else if (bi < 308) prep_dwT_dev(cv0_w, DW_A1, 9,  bi - 305);
        else if (bi < 315) prep_dwT_dev(c0_w,  DW_B1, 25, bi - 308);
        else if (bi < 322) prep_dwT_dev(cvs_w, DW_A2, 25, bi - 315);
        else               prep_dwT_dev(cs_w,  DW_B2, 49, bi - 322);
        return;
    }
    const int s  = bi - 335;
    const int b  = s & 1;
    const int br = (s >> 1) & 1;
    const int p0 = (s >> 2) * 16;
    const float* sb = x + (long)b * (128 * HW) + (long)br * (64 * HW);
    bf_t*  dhi = (bf_t*)(g_ws + (br ? XB_HI : XA_HI));
    bf_t*  dlo = (bf_t*)(g_ws + (br ? XB_LO : XA_LO));
    float* df  = g_ws + (br ? XB_F32 : XA_F32);
    const int t = threadIdx.x;
    {
        const int px = t & 15;
        const int c0 = t >> 4;
#pragma unroll
        for (int pass = 0; pass < 4; ++pass) {
            int ci = c0 + pass * 16;
            lds[px * 68 + ci] = sb[ci * HW + p0 + px];
        }
    }
    __syncthreads();
    if (t < 128) {
        int px = t >> 3, q = t & 7;
        bf8_t vh, vl;
        f4_t  f0, f1;
#pragma unroll
        for (int j = 0; j < 8; ++j) {
            float a = lds[px * 68 + q * 8 + j];
            bf_t hcast = (bf_t)a;
            vh[j] = hcast;
            vl[j] = (bf_t)(a - (float)hcast);
            if (j < 4) f0[j] = a; else f1[j - 4] = a;
        }
        long base = (((long)b * 4096 + p0 + px) * 64) + q * 8;
        *(bf8_t*)&dhi[base] = vh;
        *(bf8_t*)&dlo[base] = vl;
        *(f4_t*)&df[base]     = f0;
        *(f4_t*)&df[base + 4] = f1;
    }
}

// ---------------------------------------------------------------------------
// MFMA implicit-GEMM conv body (hi/lo split input), dynamic-LDS version.
// CPG raised (R7): each wave computes CPG cout-tiles per B-operand LDS read
// pair -> MFMA:ds_read ratio = CPG, and total row re-staging traffic drops
// as the by-grid shrinks.
// ---------------------------------------------------------------------------
template<int K, int DIL, int PAD, int NCOT, int CPG>
__device__ __forceinline__ void mfma_conv_dev(
    int bx, int by, bf_t* smem,
    int hi_off, int lo_off, int aw_off, const float* __restrict__ bias,
    int dst_off, int Cout)
{
    constexpr int COLS = 64 + 2 * PAD;
    const bf_t* shi = (const bf_t*)(g_ws + hi_off);
    const bf_t* slo = (const bf_t*)(g_ws + lo_off);
    const bf_t* aw  = (const bf_t*)(g_ws + aw_off);
    float* dst = g_ws + dst_off;
    bf_t* lds0 = smem;
    bf_t* lds1 = smem + COLS * 72;

    const int t    = threadIdx.x;
    const int lane = t & 63;
    const int wv   = t >> 6;
    const int b    = bx >> 6;
    const int h    = bx & 63;
    const int ct0  = by * CPG;

    const int n0 = lane & 15;
    const int kq = lane >> 4;

    f4_t acc[CPG];
#pragma unroll
    for (int i = 0; i < CPG; ++i) acc[i] = (f4_t){0.f, 0.f, 0.f, 0.f};

    for (int ky = 0; ky < K; ++ky) {
        const int ih = h - PAD + ky * DIL;
        __syncthreads();
        if ((unsigned)ih < 64u) {
            const long rowb = ((long)b * 4096 + ih * 64) * 64;
            for (int c = t; c < COLS * 8; c += 256) {
                int col = c >> 3, q = c & 7;
                int iw = col - PAD;
                bf8_t vh, vl;
                if ((unsigned)iw < 64u) {
                    vh = *(const bf8_t*)&shi[rowb + iw * 64 + q * 8];
                    vl = *(const bf8_t*)&slo[rowb + iw * 64 + q * 8];
                } else { vh = bf8_zero(); vl = bf8_zero(); }
                *(bf8_t*)&lds0[col * 72 + q * 8] = vh;
                *(bf8_t*)&lds1[col * 72 + q * 8] = vl;
            }
        } else {
            bf8_t z = bf8_zero();
            for (int c = t; c < COLS * 8; c += 256) {
                int col = c >> 3, q = c & 7;
                *(bf8_t*)&lds0[col * 72 + q * 8] = z;
                *(bf8_t*)&lds1[col * 72 + q * 8] = z;
            }
        }
        __syncthreads();
#pragma unroll
        for (int kx = 0; kx < K; ++kx) {
            const int tap = ky * K + kx;
            bf8_t afr[CPG][2];
#pragma unroll
            for (int ct = 0; ct < CPG; ++ct)
#pragma unroll
                for (int kh = 0; kh < 2; ++kh)
                    afr[ct][kh] = *(const bf8_t*)
                        &aw[((((long)tap * NCOT + ct0 + ct) * 2 + kh) * 64 + lane) * 8];
            const int colb = (wv * 16 + n0 + kx * DIL) * 72;
#pragma unroll
            for (int kh = 0; kh < 2; ++kh) {
                const bf8_t bh = *(const bf8_t*)&lds0[colb + kh * 32 + kq * 8];
                const bf8_t bl = *(const bf8_t*)&lds1[colb + kh * 32 + kq * 8];
#pragma unroll
                for (int ct = 0; ct < CPG; ++ct) {
                    acc[ct] = __builtin_amdgcn_mfma_f32_16x16x32_bf16(
                        afr[ct][kh], bh, acc[ct], 0, 0, 0);
                    acc[ct] = __builtin_amdgcn_mfma_f32_16x16x32_bf16(
                        afr[ct][kh], bl, acc[ct], 0, 0, 0);
                }
            }
        }
    }

    const int w = wv * 16 + n0;
#pragma unroll
    for (int ct = 0; ct < CPG; ++ct) {
#pragma unroll
        for (int r = 0; r < 4; ++r) {
            int co = (ct0 + ct) * 16 + kq * 4 + r;
            if (co < Cout)
                dst[((long)b * Cout + co) * HW + h * 64 + w] = acc[ct][r] + bias[co];
        }
    }
}

// Kernel 2: stage-1 convs, k3 CPG2 (128 blocks) / k5 CPG2 (256 blocks),
// interleaved mod 3. Grid 384.
__global__ __launch_bounds__(256) void conv_s1_kernel(
    const float* __restrict__ biasA, const float* __restrict__ biasB)
{
    extern __shared__ __align__(16) bf_t smem1[];
    const int bi = blockIdx.x;
    const int g = bi / 3, r = bi % 3;
    if (r == 0)
        mfma_conv_dev<3, 1, 1, 2, 2>(g & 127, 0, smem1,
                                     XA_HI, XA_LO, AW_A1, biasA, OFF_A, 18);
    else {
        const int s = 2 * g + (r - 1);
        mfma_conv_dev<5, 1, 2, 4, 2>(s & 127, s >> 7, smem1,
                                     XB_HI, XB_LO, AW_B1, biasB, OFF_B, 50);
    }
}

// Kernel 4: stage-2 convs, k5 CPG2 / k7 CPG4 interleaved even/odd. Grid 512.
__global__ __launch_bounds__(256) void conv_s2_kernel(
    const float* __restrict__ biasA, const float* __restrict__ biasB)
{
    extern __shared__ __align__(16) bf_t smem2[];
    const int bi = blockIdx.x;
    const int s = bi >> 1;
    if ((bi & 1) == 0)
        mfma_conv_dev<5, 3, 6, 4, 2>(s & 127, s >> 7, smem2,
                                     A1_HI, A1_LO, AW_A2, biasA, OFF_A, 50);
    else
        mfma_conv_dev<7, 3, 9, 8, 4>(s & 127, s >> 7, smem2,
                                     B1_HI, B1_LO, AW_B2, biasB, OFF_B, 98);
}

// ---------------------------------------------------------------------------
// Fused deformable sampler, single-dwordx4-per-gather edition.
//
// R1-R6 established: duration tracks DISTINCT CACHE LINES touched per
// pixel-tap (~5.6 cy/128B-line/CU), invariant to instruction count and
// occupancy. 8 lines/pixel-tap (2 rows x 512B, all bytes consumed) is the
// structural floor for NHWC-f32. This version: 1 dwordx4 wave-gather per
// pixel-tap; store epilogue split across all four 16-lane groups (R7: the
// xor16/xor32 reduction leaves every lane holding the full sums, so groups
// can store dst-px0 / dst-px1 / hilo-px0 / hilo-px1 in parallel).
// ---------------------------------------------------------------------------
template<int KK, int WRITE_HILO>
__device__ __forceinline__ void sample_fused_dev(
    int bx, float* recs, float* dwl, int src_off, int off_off, int dwt_off,
    int dst_off, int hi_off, int lo_off, int K, int pad, int dil)
{
    const int t   = threadIdx.x;
    const int pgi = ((bx & 7) << 7) | (bx >> 3);   // XCD-contiguous chunks

    // phase A: pair records for this block's 8 pixels
    for (int rec = t; rec < 8 * KK; rec += 256) {
        const int pxl = rec & 7;
        const int kk  = rec >> 3;
        const int pg  = pgi * 8 + pxl;
        const int b   = pg >> 12;
        const int p   = pg & 4095;
        const int h   = p >> 6, w = p & 63;
        const float oy = g_ws[off_off + ((long)(b * 2 * KK + 2 * kk)) * HW + p];
        const float ox = g_ws[off_off + ((long)(b * 2 * KK + 2 * kk + 1)) * HW + p];
        const float py = oy + (float)(h - pad + (kk / K) * dil);
        const float px = ox + (float)(w - pad + (kk % K) * dil);
        const float fy = floorf(py), fx = floorf(px);
        const float ly = py - fy,    lx = px - fx;
        const int y0 = (int)fy, x0 = (int)fx;
        const int y1 = y0 + 1,  x1 = x0 + 1;
        const float ry0 = ((unsigned)y0 < 64u) ? (1.f - ly) : 0.f;
        const float ry1 = ((unsigned)y1 < 64u) ? ly : 0.f;
        const float cx0 = ((unsigned)x0 < 64u) ? (1.f - lx) : 0.f;
        const float cx1 = ((unsigned)x1 < 64u) ? lx : 0.f;
        const int xbase = min(max(x0, 0), 62);
        const float sA = (xbase == x0) ? cx0 : ((xbase == x1) ? cx1 : 0.f);
        const float sB = ((xbase + 1) == x1) ? cx1
                                             : (((xbase + 1) == x0) ? cx0 : 0.f);
        const int y0c = min(max(y0, 0), 63), y1c = min(max(y1, 0), 63);
        const int a0 = (y0c * 64 + xbase) * 256;   // byte address of row-y0 pair
        const int a1 = (y1c * 64 + xbase) * 256;
        float* rp = &recs[rec * 8];
        f4_t r0, r1;
        r0[0] = ry0 * sA; r0[1] = ry0 * sB;
        r0[2] = __int_as_float(a0); r0[3] = 0.f;
        r1[0] = ry1 * sA; r1[1] = ry1 * sB;
        r1[2] = __int_as_float(a1); r1[3] = 0.f;
        *(f4_t*)rp       = r0;
        *(f4_t*)(rp + 4) = r1;
    }

    // depthwise weights -> LDS (coalesced copy, overlaps phase A latency)
    for (int e = t; e < KK * 64; e += 256) dwl[e] = g_ws[dwt_off + e];
    __syncthreads();

    // phase B: wave wv handles pixels {2wv, 2wv+1}
    const int lane = t & 63;
    const int half = (lane >> 5) & 1;  // row select
    const int sub  = (lane >> 4) & 1;  // col slot within the pair
    const int q    = lane & 15;        // channel quad (ch 4q..4q+3)
    const int wv   = t >> 6;
    const int px0  = wv * 2, px1 = wv * 2 + 1;
    const int pg0  = pgi * 8 + px0;
    const int b    = pg0 >> 12;        // both pixels share the batch (8-aligned)

    const char*  sbl = (const char*)(g_ws + src_off + ((long)b << 18))
                       + sub * 256 + q * 16;
    const float* dwp = dwl + q * 4;

    f4_t acc0 = {0.f, 0.f, 0.f, 0.f};
    f4_t acc1 = {0.f, 0.f, 0.f, 0.f};
#pragma unroll
    for (int kk = 0; kk < KK; ++kk) {
        const f4_t r0 = *(const f4_t*)&recs[(kk * 8 + px0) * 8 + half * 4];
        const f4_t r1 = *(const f4_t*)&recs[(kk * 8 + px1) * 8 + half * 4];
        const f4_t dw = *(const f4_t*)(dwp + kk * 64);
        const float w0 = sub ? r0[1] : r0[0];
        const float w1 = sub ? r1[1] : r1[0];
        const f4_t v0 = *(const f4_t*)(sbl + __float_as_int(r0[2]));
        const f4_t v1 = *(const f4_t*)(sbl + __float_as_int(r1[2]));
#pragma unroll
        for (int c = 0; c < 4; ++c) {
            acc0[c] = fmaf(dw[c] * w0, v0[c], acc0[c]);
            acc1[c] = fmaf(dw[c] * w1, v1[c], acc1[c]);
        }
    }

    // combine col slots (xor 16) then rows (xor 32); all lanes end duplicated
#pragma unroll
    for (int c = 0; c < 4; ++c) {
        acc0[c] += __shfl_xor(acc0[c], 16);
        acc0[c] += __shfl_xor(acc0[c], 32);
        acc1[c] += __shfl_xor(acc1[c], 16);
        acc1[c] += __shfl_xor(acc1[c], 32);
    }

    // store epilogue: split across lane groups (all hold the full sums)
    const int p0 = pg0 & 4095;
    const long ob0 = ((long)b * 4096 + p0) * 64 + q * 4;
    const long ob1 = ob0 + 64;                 // px1 = px0 + 1 (same batch)
    const int grp = lane >> 4;
    if (WRITE_HILO) {
        if (grp == 0) {
            *(f4_t*)&g_ws[dst_off + ob0] = acc0;
        } else if (grp == 1) {
            *(f4_t*)&g_ws[dst_off + ob1] = acc1;
        } else if (grp == 2) {
            bf4v_t h0, l0;
#pragma unroll
            for (int c = 0; c < 4; ++c) {
                bf_t hh = (bf_t)acc0[c];
                h0[c] = hh; l0[c] = (bf_t)(acc0[c] - (float)hh);
            }
            *(bf4v_t*)&((bf_t*)(g_ws + hi_off))[ob0] = h0;
            *(bf4v_t*)&((bf_t*)(g_ws + lo_off))[ob0] = l0;
        } else {
            bf4v_t h1, l1;
#pragma unroll
            for (int c = 0; c < 4; ++c) {
                bf_t hh = (bf_t)acc1[c];
                h1[c] = hh; l1[c] = (bf_t)(acc1[c] - (float)hh);
            }
            *(bf4v_t*)&((bf_t*)(g_ws + hi_off))[ob1] = h1;
            *(bf4v_t*)&((bf_t*)(g_ws + lo_off))[ob1] = l1;
        }
    } else {
        if (grp == 0)      *(f4_t*)&g_ws[dst_off + ob0] = acc0;
        else if (grp == 1) *(f4_t*)&g_ws[dst_off + ob1] = acc1;
    }
}

template<int KA, int KB, int WRITE_HILO>
__global__ __launch_bounds__(256) void sample_kernel(
    int srcA, int offA, int dwtA, int dstA, int hiA, int loA, int padA, int dilA,
    int srcB, int offB, int dwtB, int dstB, int hiB, int loB, int padB, int dilB)
{
    constexpr int KKmax = KB * KB;
    __shared__ __align__(16) float recs[8 * KKmax * 8];
    __shared__ __align__(16) float dwl[KKmax * 64];
    const int bx = blockIdx.x;
    const int s = bx >> 1;
    if ((bx & 1) == 0)       // interleaved: flattens A/B duration imbalance
        sample_fused_dev<KA * KA, WRITE_HILO>(s, recs, dwl, srcA, offA, dwtA,
                                              dstA, hiA, loA, KA, padA, dilA);
    else
        sample_fused_dev<KB * KB, WRITE_HILO>(s, recs, dwl, srcB, offB, dwtB,
                                              dstB, hiB, loB, KB, padB, dilB);
}

// ---------------------------------------------------------------------------
// Kernel 6: per-branch 1x1 conv (+bias), then out = x * result.
// ---------------------------------------------------------------------------
__global__ __launch_bounds__(256) void final_kernel(
    const float* __restrict__ x,
    int aA_off, int aB_off,
    const float* __restrict__ w1, const float* __restrict__ b1,
    const float* __restrict__ w2, const float* __restrict__ b2,
    float* __restrict__ out)
{
    __shared__ float atile[64 * 65];
    __shared__ float wlds[64 * 32];
    const int t  = threadIdx.x;
    const int p0 = blockIdx.x * 64;
    const int by = blockIdx.y;
    const int b  = blockIdx.z;
    const bool brB  = (by >> 1) != 0;
    const int  cbase = (by & 1) * 32;
    const float* a  = g_ws + (brB ? aB_off : aA_off) + (long)b * (4096 * 64);
    const float* wg = brB ? w2 : w1;
    const float* bg = brB ? b2 : b1;

    {
        const int ci = t & 63;
        const int pxg = (t >> 6) * 16;
#pragma unroll
        for (int i = 0; i < 16; ++i) {
            int px = pxg + i;
            atile[px * 65 + ci] = a[(long)(p0 + px) * 64 + ci];
        }
    }
    for (int e = t; e < 2048; e += 256) {
        int col = e & 31, ci = e >> 5;
        wlds[ci * 32 + col] = wg[(cbase + col) * 64 + ci];
    }
    __syncthreads();

    const int px  = t & 63;
    const int cog = t >> 6;
    float acc[8] = {0, 0, 0, 0, 0, 0, 0, 0};
    for (int ci = 0; ci < 64; ++ci) {
        const float av = atile[px * 65 + ci];
        const float* wr = &wlds[ci * 32 + cog * 8];
#pragma unroll
        for (int j = 0; j < 8; ++j) acc[j] = fmaf(av, wr[j], acc[j]);
    }

    const int p = p0 + px;
#pragma unroll
    for (int j = 0; j < 8; ++j) {
        const int co = cbase + cog * 8 + j;
        const int cg = (brB ? 64 : 0) + co;
        const long o = ((long)b * 128 + cg) * HW + p;
        out[o] = (acc[j] + bg[co]) * x[o];
    }
}

// ---------------------------------------------------------------------------
extern "C" void kernel_launch(void* const* d_in, const int* in_sizes, int n_in,
                              void* d_out, int out_size, void* d_ws, size_t ws_size,
                              hipStream_t stream) {
    const float* x         = (const float*)d_in[0];
    const float* cv0_off_w = (const float*)d_in[1];
    const float* cv0_off_b = (const float*)d_in[2];
    const float* cv0_w     = (const float*)d_in[3];
    const float* cvs_off_w = (const float*)d_in[4];
    const float* cvs_off_b = (const float*)d_in[5];
    const float* cvs_w     = (const float*)d_in[6];
    const float* c0_off_w  = (const float*)d_in[7];
    const float* c0_off_b  = (const float*)d_in[8];
    const float* c0_w      = (const float*)d_in[9];
    const float* cs_off_w  = (const float*)d_in[10];
    const float* cs_off_b  = (const float*)d_in[11];
    const float* cs_w      = (const float*)d_in[12];
    const float* conv1_w   = (const float*)d_in[13];
    const float* conv1_b   = (const float*)d_in[14];
    const float* conv2_w   = (const float*)d_in[15];
    const float* conv2_b   = (const float*)d_in[16];
    float* out = (float*)d_out;
    (void)d_ws; (void)ws_size;

    // 1: weight prep + x NHWC/hi-lo split
    prep_split_kernel<<<dim3(1359), 256, 0, stream>>>(
        x, cv0_off_w, c0_off_w, cvs_off_w, cs_off_w, cv0_w, c0_w, cvs_w, cs_w);

    // 2: stage-1 offset convs (k3 CPG2 + k5 CPG2, interleaved)
    conv_s1_kernel<<<dim3(384), 256, 19584, stream>>>(cv0_off_b, c0_off_b);

    // 3: stage-1 fused precompute+sampling (+ hi/lo emit)
    sample_kernel<3, 5, 1><<<dim3(2048), 256, 0, stream>>>(
        XA_F32, OFF_A, DW_A1, A1_F32, A1_HI, A1_LO, 1, 1,
        XB_F32, OFF_B, DW_B1, B1_F32, B1_HI, B1_LO, 2, 1);

    // 4: stage-2 offset convs (k5 CPG2 + k7 CPG4, interleaved)
    conv_s2_kernel<<<dim3(512), 256, 23616, stream>>>(cvs_off_b, cs_off_b);

    // 5: stage-2 fused precompute+sampling
    sample_kernel<5, 7, 0><<<dim3(2048), 256, 0, stream>>>(
        A1_F32, OFF_A, DW_A2, A2_F32, 0, 0, 6, 3,
        B1_F32, OFF_B, DW_B2, B2_F32, 0, 0, 9, 3);

    // 6: 1x1 convs + gating multiply
    final_kernel<<<dim3(64, 4, 2), 256, 0, stream>>>(
        x, A2_F32, B2_F32, conv1_w, conv1_b, conv2_w, conv2_b, out);
}